// Round 4
// baseline (705.952 us; speedup 1.0000x reference)
//
#include <hip/hip_runtime.h>
#include <hip/hip_bf16.h>

#define CH 64  // IN_C = HID_C = OUT_C = 64

// ---------- CSR build ----------

// deg histogram + per-edge rank (rank written coalesced)
__global__ void deg_rank_kernel(const int* __restrict__ dst, int* __restrict__ deg,
                                int* __restrict__ rank, int E) {
    int e = blockIdx.x * blockDim.x + threadIdx.x;
    if (e < E) rank[e] = atomicAdd(&deg[dst[e]], 1);
}

// per-block (1024) exclusive scan of rs in place; also emits dis = rsqrt(deg+1)
__global__ void scan_block_kernel(int* __restrict__ rs, int* __restrict__ bsum,
                                  float* __restrict__ dis, int n) {
    __shared__ int tmp[1024];
    int t = threadIdx.x;
    int i = blockIdx.x * 1024 + t;
    int v = (i < n) ? rs[i] : 0;
    if (i < n) dis[i] = rsqrtf((float)v + 1.0f);
    tmp[t] = v;
    __syncthreads();
    for (int off = 1; off < 1024; off <<= 1) {
        int a = (t >= off) ? tmp[t - off] : 0;
        __syncthreads();
        tmp[t] += a;
        __syncthreads();
    }
    if (i < n) rs[i] = tmp[t] - v;  // exclusive
    if (t == 1023) bsum[blockIdx.x] = tmp[1023];
}

// single-block exclusive scan of bsum (nb <= 1024)
__global__ void scan_top_kernel(int* __restrict__ bsum, int nb) {
    __shared__ int tmp[1024];
    int t = threadIdx.x;
    int v = (t < nb) ? bsum[t] : 0;
    tmp[t] = v;
    __syncthreads();
    for (int off = 1; off < 1024; off <<= 1) {
        int a = (t >= off) ? tmp[t - off] : 0;
        __syncthreads();
        tmp[t] += a;
        __syncthreads();
    }
    if (t < nb) bsum[t] = tmp[t] - v;
}

__global__ void scan_add_kernel(int* __restrict__ rs, const int* __restrict__ bsum, int n) {
    int i = blockIdx.x * blockDim.x + threadIdx.x;
    if (i < n) rs[i] += bsum[i >> 10];
}

// pre-addressed fill: no atomics; rs stays row_start
__global__ void fill_csr_kernel(const int* __restrict__ src, const int* __restrict__ dst,
                                const int* __restrict__ rs, const int* __restrict__ rank,
                                int* __restrict__ col, int E) {
    int e = blockIdx.x * blockDim.x + threadIdx.x;
    if (e < E) col[rs[dst[e]] + rank[e]] = src[e];
}

// ---------- compute ----------

// Y[r,c] = bf16( (sum_k X[r,k] * W[k,c]) * dis[r] )
// 256 thr/block = 32 rows x 64 cols; thread: 2 rows x 4 cols (8 indep acc chains).
// Per k: one ds_read_b128 of W row feeds 8 FMAs (1:8 LDS:FMA ratio).
__global__ void gemm64_scaled_kernel(const float* __restrict__ X, const float* __restrict__ W,
                                     const float* __restrict__ dis,
                                     __hip_bfloat16* __restrict__ Y, int n) {
    __shared__ float Ws[CH * CH];
    {
        float4* w4 = (float4*)Ws;
        const float4* g4 = (const float4*)W;
        for (int i = threadIdx.x; i < CH * CH / 4; i += 256) w4[i] = g4[i];
    }
    __syncthreads();
    int t = threadIdx.x;
    int cbase = (t & 15) * 4;
    int r0 = blockIdx.x * 32 + (t >> 4) * 2;  // rows r0, r0+1
    if (r0 >= n) return;
    bool has2 = (r0 + 1 < n);
    const float4* x0 = (const float4*)(X + (size_t)r0 * CH);
    const float4* x1 = (const float4*)(X + (size_t)(has2 ? r0 + 1 : r0) * CH);

    float a00 = 0.f, a01 = 0.f, a02 = 0.f, a03 = 0.f;
    float a10 = 0.f, a11 = 0.f, a12 = 0.f, a13 = 0.f;
#pragma unroll
    for (int k4 = 0; k4 < CH / 4; ++k4) {
        float4 xa = x0[k4];
        float4 xb = x1[k4];
        float xav[4] = {xa.x, xa.y, xa.z, xa.w};
        float xbv[4] = {xb.x, xb.y, xb.z, xb.w};
#pragma unroll
        for (int kk = 0; kk < 4; ++kk) {
            float4 wv = *(const float4*)&Ws[(4 * k4 + kk) * CH + cbase];
            float s0 = xav[kk], s1 = xbv[kk];
            a00 += s0 * wv.x; a01 += s0 * wv.y; a02 += s0 * wv.z; a03 += s0 * wv.w;
            a10 += s1 * wv.x; a11 += s1 * wv.y; a12 += s1 * wv.z; a13 += s1 * wv.w;
        }
    }
    float d0 = dis[r0];
    __hip_bfloat162* y0 = (__hip_bfloat162*)(Y + (size_t)r0 * CH + cbase);
    y0[0] = __hip_bfloat162{__float2bfloat16(a00 * d0), __float2bfloat16(a01 * d0)};
    y0[1] = __hip_bfloat162{__float2bfloat16(a02 * d0), __float2bfloat16(a03 * d0)};
    if (has2) {
        float d1 = dis[r0 + 1];
        __hip_bfloat162* y1 = (__hip_bfloat162*)(Y + (size_t)(r0 + 1) * CH + cbase);
        y1[0] = __hip_bfloat162{__float2bfloat16(a10 * d1), __float2bfloat16(a11 * d1)};
        y1[1] = __hip_bfloat162{__float2bfloat16(a12 * d1), __float2bfloat16(a13 * d1)};
    }
}

// one wave per node, lane = channel (bf16 gather, fp32 accumulate):
// out[d,c] = relu( dis[d] * (sum_{e in row d} xws[col[e],c] + xws[d,c]) + b[c] )
__global__ void gather_kernel(const __hip_bfloat16* __restrict__ xws, const int* __restrict__ col,
                              const int* __restrict__ rs, const float* __restrict__ dis,
                              const float* __restrict__ b, float* __restrict__ out,
                              int n, int E) {
    int wid = (blockIdx.x * blockDim.x + threadIdx.x) >> 6;
    int lane = threadIdx.x & 63;
    if (wid >= n) return;
    int beg = rs[wid];
    int end = (wid + 1 < n) ? rs[wid + 1] : E;
    float acc = 0.0f;
    int e = beg;
    for (; e + 3 < end; e += 4) {
        int s0 = col[e], s1 = col[e + 1], s2 = col[e + 2], s3 = col[e + 3];
        float v0 = __bfloat162float(xws[s0 * CH + lane]);
        float v1 = __bfloat162float(xws[s1 * CH + lane]);
        float v2 = __bfloat162float(xws[s2 * CH + lane]);
        float v3 = __bfloat162float(xws[s3 * CH + lane]);
        acc += v0 + v1 + v2 + v3;
    }
    for (; e < end; ++e) acc += __bfloat162float(xws[col[e] * CH + lane]);
    float d = dis[wid];
    float v = d * (acc + __bfloat162float(xws[wid * CH + lane])) + b[lane];
    out[wid * CH + lane] = fmaxf(v, 0.0f);
}

// gather + relu + per-block LN partial sums
__global__ void gather_stats_kernel(const __hip_bfloat16* __restrict__ xws,
                                    const int* __restrict__ col, const int* __restrict__ rs,
                                    const float* __restrict__ dis, const float* __restrict__ b,
                                    float* __restrict__ out, int n, int E,
                                    float* __restrict__ sums, float* __restrict__ sqs) {
    int wid = (blockIdx.x * blockDim.x + threadIdx.x) >> 6;
    int lane = threadIdx.x & 63;
    float v = 0.0f;
    if (wid < n) {
        int beg = rs[wid];
        int end = (wid + 1 < n) ? rs[wid + 1] : E;
        float acc = 0.0f;
        int e = beg;
        for (; e + 3 < end; e += 4) {
            int s0 = col[e], s1 = col[e + 1], s2 = col[e + 2], s3 = col[e + 3];
            float v0 = __bfloat162float(xws[s0 * CH + lane]);
            float v1 = __bfloat162float(xws[s1 * CH + lane]);
            float v2 = __bfloat162float(xws[s2 * CH + lane]);
            float v3 = __bfloat162float(xws[s3 * CH + lane]);
            acc += v0 + v1 + v2 + v3;
        }
        for (; e < end; ++e) acc += __bfloat162float(xws[col[e] * CH + lane]);
        float d = dis[wid];
        v = fmaxf(d * (acc + __bfloat162float(xws[wid * CH + lane])) + b[lane], 0.0f);
        out[wid * CH + lane] = v;
    }
    float s = v, sq = v * v;
#pragma unroll
    for (int off = 32; off > 0; off >>= 1) {
        s += __shfl_down(s, off, 64);
        sq += __shfl_down(sq, off, 64);
    }
    __shared__ float ls[4], lq[4];
    int w = threadIdx.x >> 6;
    if ((threadIdx.x & 63) == 0) { ls[w] = s; lq[w] = sq; }
    __syncthreads();
    if (threadIdx.x == 0) {
        sums[blockIdx.x] = ls[0] + ls[1] + ls[2] + ls[3];
        sqs[blockIdx.x] = lq[0] + lq[1] + lq[2] + lq[3];
    }
}

// single block: reduce nb partials -> {scale, offset}
__global__ void reduce_final_kernel(const float* __restrict__ sums, const float* __restrict__ sqs,
                                    int nb, float n_total, const float* __restrict__ lnw,
                                    const float* __restrict__ lnb, float* __restrict__ so) {
    float s = 0.0f, sq = 0.0f;
    for (int i = threadIdx.x; i < nb; i += 1024) { s += sums[i]; sq += sqs[i]; }
#pragma unroll
    for (int off = 32; off > 0; off >>= 1) {
        s += __shfl_down(s, off, 64);
        sq += __shfl_down(sq, off, 64);
    }
    __shared__ float ls[16], lq[16];
    int w = threadIdx.x >> 6;
    if ((threadIdx.x & 63) == 0) { ls[w] = s; lq[w] = sq; }
    __syncthreads();
    if (threadIdx.x == 0) {
        float ts = 0.0f, tq = 0.0f;
        for (int i = 0; i < 16; ++i) { ts += ls[i]; tq += lq[i]; }
        float mean = ts / n_total;
        float var = tq / n_total - mean * mean;
        float scale = rsqrtf(var + 1e-5f) * lnw[0];
        so[0] = scale;
        so[1] = lnb[0] - mean * scale;
    }
}

__global__ void norm_kernel(float* __restrict__ x, int n4, const float* __restrict__ so) {
    int i = blockIdx.x * blockDim.x + threadIdx.x;
    if (i >= n4) return;
    float scale = so[0], off = so[1];
    float4* x4 = (float4*)x;
    float4 v = x4[i];
    v.x = v.x * scale + off;
    v.y = v.y * scale + off;
    v.z = v.z * scale + off;
    v.w = v.w * scale + off;
    x4[i] = v;
}

extern "C" void kernel_launch(void* const* d_in, const int* in_sizes, int n_in,
                              void* d_out, int out_size, void* d_ws, size_t ws_size,
                              hipStream_t stream) {
    const float* X   = (const float*)d_in[0];
    const int*   edg = (const int*)d_in[1];   // [2,E]: src row then dst row
    const float* W1  = (const float*)d_in[2];
    const float* b1  = (const float*)d_in[3];
    const float* W2  = (const float*)d_in[4];
    const float* b2  = (const float*)d_in[5];
    const float* lnw = (const float*)d_in[6];
    const float* lnb = (const float*)d_in[7];
    float* out = (float*)d_out;

    const int N  = in_sizes[0] / CH;   // 100000
    const int E  = in_sizes[1] / 2;    // 1600000
    const int NC = N * CH;             // 6.4M
    const int nGatherBlk = (N * CH + 255) / 256;  // 25000

    const int* srcp = edg;
    const int* dstp = edg + E;

    // workspace layout (4B units)
    int*   rs   = (int*)d_ws;                        // N  (deg -> row_start)
    int*   rank = rs + N;                            // E
    int*   col  = rank + E;                          // E
    float* dis  = (float*)(col + E);                 // N
    __hip_bfloat16* xws = (__hip_bfloat16*)(dis + N); // NC bf16
    float* h    = (float*)(xws + NC);                // NC floats
    int*   bsum = (int*)(h + NC);                    // 1024
    float* sums = (float*)(bsum + 1024);             // nGatherBlk
    float* sqs  = sums + nGatherBlk;                 // nGatherBlk
    float* so   = sqs + nGatherBlk;                  // 2 {scale, offset}

    const int B = 256;
    const int nScanBlk = (N + 1023) / 1024;          // 98

    // ---- CSR build ----
    hipMemsetAsync(rs, 0, (size_t)N * sizeof(int), stream);
    deg_rank_kernel<<<(E + B - 1) / B, B, 0, stream>>>(dstp, rs, rank, E);
    scan_block_kernel<<<nScanBlk, 1024, 0, stream>>>(rs, bsum, dis, N);
    scan_top_kernel<<<1, 1024, 0, stream>>>(bsum, nScanBlk);
    scan_add_kernel<<<(N + B - 1) / B, B, 0, stream>>>(rs, bsum, N);
    fill_csr_kernel<<<(E + B - 1) / B, B, 0, stream>>>(srcp, dstp, rs, rank, col, E);
    // rs holds row_start (exclusive); row i spans [rs[i], rs[i+1]), rs[N] == E

    // ---- layer 1 ----
    gemm64_scaled_kernel<<<(N + 31) / 32, B, 0, stream>>>(X, W1, dis, xws, N);
    gather_kernel<<<nGatherBlk, B, 0, stream>>>(xws, col, rs, dis, b1, h, N, E);

    // ---- layer 2 (LN stats fused into gather epilogue) ----
    gemm64_scaled_kernel<<<(N + 31) / 32, B, 0, stream>>>(h, W2, dis, xws, N);
    gather_stats_kernel<<<nGatherBlk, B, 0, stream>>>(xws, col, rs, dis, b2, out, N, E, sums, sqs);

    // ---- graph layernorm ----
    reduce_final_kernel<<<1, 1024, 0, stream>>>(sums, sqs, nGatherBlk, (float)NC, lnw, lnb, so);
    norm_kernel<<<(NC / 4 + B - 1) / B, B, 0, stream>>>(out, NC / 4, so);
}